// Round 5
// baseline (105.281 us; speedup 1.0000x reference)
//
#include <hip/hip_runtime.h>
#include <float.h>

#define NS 131072
#define DD 64
#define KK 256
#define CPAD 72     // 64 + 8 bf16 pad -> 144B row stride, breaks stride-128 bank conflict
#define NSTAT 16896 // KK + KK*DD + KK  (cnt | sums | ssq)

typedef __attribute__((ext_vector_type(8))) short bf16x8;
typedef __attribute__((ext_vector_type(4))) float f32x4;

// d_out layout (float32 values):
//   [0, NS)                      assignments (as float)
//   [NS, 2*NS)                   min_dists
//   [2*NS, 2*NS+KK)              leaf_counts
//   [2*NS+KK, +KK*DD)            leaf_sums
//   [2*NS+KK+KK*DD, +KK)         leaf_sum_sq_dist

__global__ void zero_buf(float* __restrict__ p, int n) {
    int i = blockIdx.x * 256 + threadIdx.x;
    if (i < n) p[i] = 0.f;
}

__global__ void reduce_ws(const float* __restrict__ ws, float* __restrict__ o_stats,
                          int ncopy, int split) {
    int gid = blockIdx.x * 256 + threadIdx.x;
    if (gid >= split * NSTAT) return;
    int q = gid / NSTAT, e = gid - q * NSTAT;
    int per = ncopy / split;
    float s = 0.f;
    for (int j = q * per; j < (q + 1) * per; ++j) s += ws[(size_t)j * NSTAT + e];
    atomicAdd(&o_stats[e], s);
}

__device__ inline unsigned short f2bf(float f) {
    unsigned u = __float_as_uint(f);
    u += 0x7FFFu + ((u >> 16) & 1u);          // round-to-nearest-even
    return (unsigned short)(u >> 16);
}
__device__ inline float bf2f(unsigned short b) {
    return __uint_as_float(((unsigned)b) << 16);
}

// ---------------- K1: MFMA argmin, high occupancy ----------------
// 1024 blocks x 256 threads (4 waves); wave handles 32 samples.
__global__ __launch_bounds__(256, 4)
void deepect_argmin(const float* __restrict__ mb, const float* __restrict__ ctr,
                    float* __restrict__ out) {
    __shared__ __align__(16) unsigned short s_ctr[KK][CPAD];  // 36 KB
    __shared__ float s_csq[KK];

    const int tid  = threadIdx.x;
    const int lane = tid & 63;
    const int w    = tid >> 6;       // wave 0..3
    const int g    = lane >> 4;      // 16-lane group 0..3
    const int c16  = lane & 15;

    // stage centers fp32 -> bf16 LDS (coalesced float4)
    for (int idx = tid; idx < KK * 16; idx += 256) {
        int row = idx >> 4, f4 = idx & 15;
        float4 v = ((const float4*)(ctr + row * DD))[f4];
        ushort4 b;
        b.x = f2bf(v.x); b.y = f2bf(v.y); b.z = f2bf(v.z); b.w = f2bf(v.w);
        *(ushort4*)&s_ctr[row][f4 * 4] = b;
    }
    __syncthreads();

    // |c|^2 from bf16 values (consistent with MFMA dot); one center per thread
    {
        float acc = 0.f;
        #pragma unroll
        for (int j = 0; j < 16; ++j) {
            ushort4 b = *(ushort4*)&s_ctr[tid][j * 4];
            float x0 = bf2f(b.x), x1 = bf2f(b.y), x2 = bf2f(b.z), x3 = bf2f(b.w);
            acc += x0 * x0 + x1 * x1 + x2 * x2 + x3 * x3;
        }
        s_csq[tid] = acc;
    }
    __syncthreads();

    float csqh[16];
    #pragma unroll
    for (int t = 0; t < 16; ++t) csqh[t] = -0.5f * s_csq[t * 16 + c16];

    const int sbase = blockIdx.x * 128 + w * 32;

    // A fragments straight from global fp32; per-lane partial |x|^2, reduced over g
    // A[row][k]: row = lane&15, k = g*8 + j (+32*ks)
    bf16x8 afr[2][2];
    float  xsq_rt[2];
    #pragma unroll
    for (int rt = 0; rt < 2; ++rt) {
        float px = 0.f;
        #pragma unroll
        for (int ks = 0; ks < 2; ++ks) {
            const float* rp = mb + (size_t)(sbase + rt * 16 + c16) * DD + g * 8 + ks * 32;
            float4 a = ((const float4*)rp)[0];
            float4 b = ((const float4*)rp)[1];
            bf16x8 f;
            f[0] = (short)f2bf(a.x); f[1] = (short)f2bf(a.y);
            f[2] = (short)f2bf(a.z); f[3] = (short)f2bf(a.w);
            f[4] = (short)f2bf(b.x); f[5] = (short)f2bf(b.y);
            f[6] = (short)f2bf(b.z); f[7] = (short)f2bf(b.w);
            afr[rt][ks] = f;
            // bf16-consistent xsq (matches the MFMA dot precision)
            float q0 = bf2f(f2bf(a.x)), q1 = bf2f(f2bf(a.y)), q2 = bf2f(f2bf(a.z)), q3 = bf2f(f2bf(a.w));
            float q4 = bf2f(f2bf(b.x)), q5 = bf2f(f2bf(b.y)), q6 = bf2f(f2bf(b.z)), q7 = bf2f(f2bf(b.w));
            px += q0*q0 + q1*q1 + q2*q2 + q3*q3 + q4*q4 + q5*q5 + q6*q6 + q7*q7;
        }
        px += __shfl_xor(px, 16, 64);
        px += __shfl_xor(px, 32, 64);   // sum over the 4 g-lanes with same c16
        xsq_rt[rt] = px;
    }

    float bestv[2][4];
    int   besti[2][4];
    #pragma unroll
    for (int rt = 0; rt < 2; ++rt)
        #pragma unroll
        for (int r = 0; r < 4; ++r) { bestv[rt][r] = -FLT_MAX; besti[rt][r] = 0; }

    // 16 col-tiles of 16 centers: argmax of x.c - |c|^2/2
    #pragma unroll
    for (int t = 0; t < 16; ++t) {
        bf16x8 b0 = *(bf16x8*)&s_ctr[t * 16 + c16][g * 8];
        bf16x8 b1 = *(bf16x8*)&s_ctr[t * 16 + c16][g * 8 + 32];
        const int colidx = t * 16 + c16;
        #pragma unroll
        for (int rt = 0; rt < 2; ++rt) {
            f32x4 acc;
            acc[0] = csqh[t]; acc[1] = csqh[t]; acc[2] = csqh[t]; acc[3] = csqh[t];
            acc = __builtin_amdgcn_mfma_f32_16x16x32_bf16(afr[rt][0], b0, acc, 0, 0, 0);
            acc = __builtin_amdgcn_mfma_f32_16x16x32_bf16(afr[rt][1], b1, acc, 0, 0, 0);
            // C[row][col]: col = lane&15 (center), row = g*4 + r (sample)
            #pragma unroll
            for (int r = 0; r < 4; ++r) {
                if (acc[r] > bestv[rt][r]) { bestv[rt][r] = acc[r]; besti[rt][r] = colidx; }
            }
        }
    }

    float* o_assign = out;
    float* o_mind   = out + NS;

    #pragma unroll
    for (int rt = 0; rt < 2; ++rt) {
        #pragma unroll
        for (int r = 0; r < 4; ++r) {
            float v  = bestv[rt][r];
            int   bi = besti[rt][r];
            #pragma unroll
            for (int off = 1; off < 16; off <<= 1) {
                float ov = __shfl_xor(v, off, 64);
                int   oi = __shfl_xor(bi, off, 64);
                if (ov > v || (ov == v && oi < bi)) { v = ov; bi = oi; }
            }
            // xsq for C-row g*4+r lives in the lane with c16 == g*4+r (same group)
            int src = (lane & 48) | (g * 4 + r);
            float xq = __shfl(xsq_rt[rt], src, 64);
            float dsq = fmaxf(xq - 2.0f * v, 0.f);
            if (c16 == 0) {
                int s = sbase + rt * 16 + g * 4 + r;
                o_assign[s] = (float)bi;
                o_mind[s]   = sqrtf(dsq);
            }
        }
    }
}

// ---------------- K2: per-leaf statistics ----------------
// 256 blocks x 512 threads, one sample per thread.
__global__ __launch_bounds__(512)
void deepect_stats(const float* __restrict__ mb, const float* __restrict__ out,
                   float* __restrict__ wsdst, int ncopy) {
    __shared__ float s_cnt[KK];
    __shared__ float s_ssq[KK];
    __shared__ float s_sum[KK][65];

    const int tid = threadIdx.x;
    for (int idx = tid; idx < KK; idx += 512) { s_cnt[idx] = 0.f; s_ssq[idx] = 0.f; }
    for (int idx = tid; idx < KK * 65; idx += 512) ((float*)s_sum)[idx] = 0.f;
    __syncthreads();

    const int i = blockIdx.x * 512 + tid;
    const int bi = (int)out[i];           // assignment (exact small int as float)
    const float md = out[NS + i];
    const float4* xr = (const float4*)(mb + (size_t)i * DD);

    atomicAdd(&s_cnt[bi], 1.0f);
    atomicAdd(&s_ssq[bi], md * md);       // exactly min_dists^2 as in reference
    #pragma unroll
    for (int j = 0; j < 16; ++j) {
        float4 v = xr[j];
        atomicAdd(&s_sum[bi][4 * j + 0], v.x);
        atomicAdd(&s_sum[bi][4 * j + 1], v.y);
        atomicAdd(&s_sum[bi][4 * j + 2], v.z);
        atomicAdd(&s_sum[bi][4 * j + 3], v.w);
    }
    __syncthreads();

    // flush block partials into one of `ncopy` ws copies
    const size_t cb = (size_t)(blockIdx.x & (ncopy - 1)) * NSTAT;
    for (int idx = tid; idx < KK; idx += 512) {
        atomicAdd(&wsdst[cb + idx], s_cnt[idx]);
        atomicAdd(&wsdst[cb + KK + KK * DD + idx], s_ssq[idx]);
    }
    for (int idx = tid; idx < KK * DD; idx += 512) {
        atomicAdd(&wsdst[cb + KK + idx], s_sum[idx >> 6][idx & 63]);
    }
}

extern "C" void kernel_launch(void* const* d_in, const int* in_sizes, int n_in,
                              void* d_out, int out_size, void* d_ws, size_t ws_size,
                              hipStream_t stream) {
    const float* mb  = (const float*)d_in[0];
    const float* ctr = (const float*)d_in[1];
    float* out = (float*)d_out;
    float* o_stats = out + 2 * NS;

    const int NCOPY = 64;
    const bool use_ws = ws_size >= (size_t)NCOPY * NSTAT * sizeof(float);

    hipLaunchKernelGGL(zero_buf, dim3((NSTAT + 255) / 256), dim3(256), 0, stream,
                       o_stats, NSTAT);
    hipLaunchKernelGGL(deepect_argmin, dim3(NS / 128), dim3(256), 0, stream,
                       mb, ctr, out);

    if (use_ws) {
        float* ws = (float*)d_ws;
        hipLaunchKernelGGL(zero_buf, dim3((NCOPY * NSTAT + 255) / 256), dim3(256), 0,
                           stream, ws, NCOPY * NSTAT);
        hipLaunchKernelGGL(deepect_stats, dim3(NS / 512), dim3(512), 0, stream,
                           mb, out, ws, NCOPY);
        const int SPLIT = 4;
        hipLaunchKernelGGL(reduce_ws, dim3((SPLIT * NSTAT + 255) / 256), dim3(256), 0,
                           stream, ws, o_stats, NCOPY, SPLIT);
    } else {
        hipLaunchKernelGGL(deepect_stats, dim3(NS / 512), dim3(512), 0, stream,
                           mb, out, o_stats, 1);
    }
}

// Round 6
// 99.001 us; speedup vs baseline: 1.0634x; 1.0634x over previous
//
#include <hip/hip_runtime.h>
#include <float.h>

#define NS 131072
#define DD 64
#define KK 256
#define CPAD 72     // 64 + 8 bf16 pad -> 144B row stride, breaks stride-128 bank conflict
#define NSTAT 16896 // KK + KK*DD + KK  (cnt | sums | ssq)

typedef __attribute__((ext_vector_type(8))) short bf16x8;
typedef __attribute__((ext_vector_type(4))) float f32x4;

// d_out layout (float32 values):
//   [0, NS)                      assignments (as float)
//   [NS, 2*NS)                   min_dists
//   [2*NS, 2*NS+KK)              leaf_counts
//   [2*NS+KK, +KK*DD)            leaf_sums
//   [2*NS+KK+KK*DD, +KK)         leaf_sum_sq_dist

__global__ void zero_buf(float* __restrict__ p, int n) {
    int i = blockIdx.x * 256 + threadIdx.x;
    if (i < n) p[i] = 0.f;
}

// non-atomic: o_stats[e] = sum over ncopy copies of ws[j*NSTAT + e]
__global__ void reduce_ws(const float* __restrict__ ws, float* __restrict__ o_stats,
                          int ncopy) {
    int e = blockIdx.x * 256 + threadIdx.x;
    if (e >= NSTAT) return;
    float s = 0.f;
    #pragma unroll 4
    for (int j = 0; j < ncopy; ++j) s += ws[(size_t)j * NSTAT + e];
    o_stats[e] = s;
}

__device__ inline unsigned short f2bf(float f) {
    unsigned u = __float_as_uint(f);
    u += 0x7FFFu + ((u >> 16) & 1u);          // round-to-nearest-even
    return (unsigned short)(u >> 16);
}
__device__ inline float bf2f(unsigned short b) {
    return __uint_as_float(((unsigned)b) << 16);
}

// ---------------- K1: MFMA argmin ----------------
// 512 blocks x 512 threads (8 waves); wave handles 32 samples; block 256 samples.
__global__ __launch_bounds__(512, 2)
void deepect_argmin(const float* __restrict__ mb, const float* __restrict__ ctr,
                    float* __restrict__ out) {
    __shared__ __align__(16) unsigned short s_ctr[KK][CPAD];  // 36 KB
    __shared__ float s_csq[KK];

    const int tid  = threadIdx.x;
    const int lane = tid & 63;
    const int w    = tid >> 6;       // wave 0..7
    const int g    = lane >> 4;      // 16-lane group 0..3
    const int c16  = lane & 15;

    // stage centers fp32 -> bf16 LDS (coalesced float4)
    for (int idx = tid; idx < KK * 16; idx += 512) {
        int row = idx >> 4, f4 = idx & 15;
        float4 v = ((const float4*)(ctr + row * DD))[f4];
        ushort4 b;
        b.x = f2bf(v.x); b.y = f2bf(v.y); b.z = f2bf(v.z); b.w = f2bf(v.w);
        *(ushort4*)&s_ctr[row][f4 * 4] = b;
    }
    __syncthreads();

    // |c|^2 from bf16 values (consistent with MFMA dot); one center per thread
    if (tid < KK) {
        float acc = 0.f;
        #pragma unroll
        for (int j = 0; j < 16; ++j) {
            ushort4 b = *(ushort4*)&s_ctr[tid][j * 4];
            float x0 = bf2f(b.x), x1 = bf2f(b.y), x2 = bf2f(b.z), x3 = bf2f(b.w);
            acc += x0 * x0 + x1 * x1 + x2 * x2 + x3 * x3;
        }
        s_csq[tid] = acc;
    }
    __syncthreads();

    float csqh[16];
    #pragma unroll
    for (int t = 0; t < 16; ++t) csqh[t] = -0.5f * s_csq[t * 16 + c16];

    const int sbase = blockIdx.x * 256 + w * 32;

    // A fragments straight from global fp32; per-lane partial |x|^2, reduced over g
    // A[row][k]: row = lane&15, k = g*8 + j (+32*ks)
    bf16x8 afr[2][2];
    float  xsq_rt[2];
    #pragma unroll
    for (int rt = 0; rt < 2; ++rt) {
        float px = 0.f;
        #pragma unroll
        for (int ks = 0; ks < 2; ++ks) {
            const float* rp = mb + (size_t)(sbase + rt * 16 + c16) * DD + g * 8 + ks * 32;
            float4 a = ((const float4*)rp)[0];
            float4 b = ((const float4*)rp)[1];
            bf16x8 f;
            f[0] = (short)f2bf(a.x); f[1] = (short)f2bf(a.y);
            f[2] = (short)f2bf(a.z); f[3] = (short)f2bf(a.w);
            f[4] = (short)f2bf(b.x); f[5] = (short)f2bf(b.y);
            f[6] = (short)f2bf(b.z); f[7] = (short)f2bf(b.w);
            afr[rt][ks] = f;
            float q0 = bf2f(f2bf(a.x)), q1 = bf2f(f2bf(a.y)), q2 = bf2f(f2bf(a.z)), q3 = bf2f(f2bf(a.w));
            float q4 = bf2f(f2bf(b.x)), q5 = bf2f(f2bf(b.y)), q6 = bf2f(f2bf(b.z)), q7 = bf2f(f2bf(b.w));
            px += q0*q0 + q1*q1 + q2*q2 + q3*q3 + q4*q4 + q5*q5 + q6*q6 + q7*q7;
        }
        px += __shfl_xor(px, 16, 64);
        px += __shfl_xor(px, 32, 64);   // sum over the 4 g-lanes with same c16
        xsq_rt[rt] = px;
    }

    float bestv[2][4];
    int   besti[2][4];
    #pragma unroll
    for (int rt = 0; rt < 2; ++rt)
        #pragma unroll
        for (int r = 0; r < 4; ++r) { bestv[rt][r] = -FLT_MAX; besti[rt][r] = 0; }

    // 16 col-tiles of 16 centers: argmax of x.c - |c|^2/2
    #pragma unroll
    for (int t = 0; t < 16; ++t) {
        bf16x8 b0 = *(bf16x8*)&s_ctr[t * 16 + c16][g * 8];
        bf16x8 b1 = *(bf16x8*)&s_ctr[t * 16 + c16][g * 8 + 32];
        const int colidx = t * 16 + c16;
        #pragma unroll
        for (int rt = 0; rt < 2; ++rt) {
            f32x4 acc;
            acc[0] = csqh[t]; acc[1] = csqh[t]; acc[2] = csqh[t]; acc[3] = csqh[t];
            acc = __builtin_amdgcn_mfma_f32_16x16x32_bf16(afr[rt][0], b0, acc, 0, 0, 0);
            acc = __builtin_amdgcn_mfma_f32_16x16x32_bf16(afr[rt][1], b1, acc, 0, 0, 0);
            // C[row][col]: col = lane&15 (center), row = g*4 + r (sample)
            #pragma unroll
            for (int r = 0; r < 4; ++r) {
                if (acc[r] > bestv[rt][r]) { bestv[rt][r] = acc[r]; besti[rt][r] = colidx; }
            }
        }
    }

    float* o_assign = out;
    float* o_mind   = out + NS;

    #pragma unroll
    for (int rt = 0; rt < 2; ++rt) {
        #pragma unroll
        for (int r = 0; r < 4; ++r) {
            float v  = bestv[rt][r];
            int   bi = besti[rt][r];
            #pragma unroll
            for (int off = 1; off < 16; off <<= 1) {
                float ov = __shfl_xor(v, off, 64);
                int   oi = __shfl_xor(bi, off, 64);
                if (ov > v || (ov == v && oi < bi)) { v = ov; bi = oi; }
            }
            // xsq for C-row g*4+r lives in the lane with c16 == g*4+r (same group)
            int src = (lane & 48) | (g * 4 + r);
            float xq = __shfl(xsq_rt[rt], src, 64);
            float dsq = fmaxf(xq - 2.0f * v, 0.f);
            if (c16 == 0) {
                int s = sbase + rt * 16 + g * 4 + r;
                o_assign[s] = (float)bi;
                o_mind[s]   = sqrtf(dsq);
            }
        }
    }
}

// ---------------- K2: per-leaf statistics ----------------
// 256 blocks x 512 threads; 16-lane group processes 16 samples (coalesced reads).
// mode 0: plain-store partials to private ws copy; mode 1: atomic into copy blockIdx&(ncopy-1)
__global__ __launch_bounds__(512)
void deepect_stats(const float* __restrict__ mb, const float* __restrict__ out,
                   float* __restrict__ wsdst, int ncopy, int mode) {
    __shared__ float s_cnt[KK];
    __shared__ float s_ssq[KK];
    __shared__ float s_sum[KK][65];

    const int tid = threadIdx.x;
    for (int idx = tid; idx < KK; idx += 512) { s_cnt[idx] = 0.f; s_ssq[idx] = 0.f; }
    for (int idx = tid; idx < KK * 65; idx += 512) ((float*)s_sum)[idx] = 0.f;
    __syncthreads();

    const int grp = tid >> 4;        // 0..31
    const int d4  = tid & 15;        // float4 index within row
    const int ibase = blockIdx.x * 512 + grp * 16;

    #pragma unroll 4
    for (int s = 0; s < 16; ++s) {
        const int i = ibase + s;
        const int bi = (int)out[i];                       // broadcast within group
        float4 v = ((const float4*)(mb + (size_t)i * DD))[d4];  // group reads 256B contiguous
        atomicAdd(&s_sum[bi][d4 * 4 + 0], v.x);
        atomicAdd(&s_sum[bi][d4 * 4 + 1], v.y);
        atomicAdd(&s_sum[bi][d4 * 4 + 2], v.z);
        atomicAdd(&s_sum[bi][d4 * 4 + 3], v.w);
        if (d4 == 0) {
            const float md = out[NS + i];
            atomicAdd(&s_cnt[bi], 1.0f);
            atomicAdd(&s_ssq[bi], md * md);               // exactly min_dists^2
        }
    }
    __syncthreads();

    if (mode == 0) {
        // private copy, plain coalesced stores
        float* dst = wsdst + (size_t)blockIdx.x * NSTAT;
        for (int idx = tid; idx < KK; idx += 512) {
            dst[idx] = s_cnt[idx];
            dst[KK + KK * DD + idx] = s_ssq[idx];
        }
        for (int idx = tid; idx < KK * DD; idx += 512)
            dst[KK + idx] = s_sum[idx >> 6][idx & 63];
    } else {
        const size_t cb = (size_t)(blockIdx.x & (ncopy - 1)) * NSTAT;
        for (int idx = tid; idx < KK; idx += 512) {
            atomicAdd(&wsdst[cb + idx], s_cnt[idx]);
            atomicAdd(&wsdst[cb + KK + KK * DD + idx], s_ssq[idx]);
        }
        for (int idx = tid; idx < KK * DD; idx += 512)
            atomicAdd(&wsdst[cb + KK + idx], s_sum[idx >> 6][idx & 63]);
    }
}

extern "C" void kernel_launch(void* const* d_in, const int* in_sizes, int n_in,
                              void* d_out, int out_size, void* d_ws, size_t ws_size,
                              hipStream_t stream) {
    const float* mb  = (const float*)d_in[0];
    const float* ctr = (const float*)d_in[1];
    float* out = (float*)d_out;
    float* o_stats = out + 2 * NS;
    float* ws = (float*)d_ws;

    hipLaunchKernelGGL(deepect_argmin, dim3(NS / 256), dim3(512), 0, stream,
                       mb, ctr, out);

    const size_t need256 = (size_t)256 * NSTAT * sizeof(float);  // 17.3 MB
    const size_t need64  = (size_t)64  * NSTAT * sizeof(float);  //  4.3 MB

    if (ws_size >= need256) {
        // fast path: private copies, no global atomics anywhere
        hipLaunchKernelGGL(deepect_stats, dim3(NS / 512), dim3(512), 0, stream,
                           mb, out, ws, 256, 0);
        hipLaunchKernelGGL(reduce_ws, dim3((NSTAT + 255) / 256), dim3(256), 0, stream,
                           ws, o_stats, 256);
    } else if (ws_size >= need64) {
        hipLaunchKernelGGL(zero_buf, dim3((64 * NSTAT + 255) / 256), dim3(256), 0,
                           stream, ws, 64 * NSTAT);
        hipLaunchKernelGGL(deepect_stats, dim3(NS / 512), dim3(512), 0, stream,
                           mb, out, ws, 64, 1);
        hipLaunchKernelGGL(reduce_ws, dim3((NSTAT + 255) / 256), dim3(256), 0, stream,
                           ws, o_stats, 64);
    } else {
        hipLaunchKernelGGL(zero_buf, dim3((NSTAT + 255) / 256), dim3(256), 0, stream,
                           o_stats, NSTAT);
        hipLaunchKernelGGL(deepect_stats, dim3(NS / 512), dim3(512), 0, stream,
                           mb, out, o_stats, 1, 1);
    }
}

// Round 7
// 85.268 us; speedup vs baseline: 1.2347x; 1.1611x over previous
//
#include <hip/hip_runtime.h>
#include <float.h>

#define NS 131072
#define DD 64
#define KK 256
#define CPAD 72     // argmin center tile pad (unchanged, verified)
#define NSTAT 16896 // 256 * 66  (== KK + KK*DD + KK values)
#define XTS 264     // xT row stride in bf16: 528B rows -> 16B-aligned, uniform b128 banking
#define XTSW 132    // XTS/2 dwords

typedef __attribute__((ext_vector_type(8))) short bf16x8;
typedef __attribute__((ext_vector_type(4))) float f32x4;
typedef __attribute__((ext_vector_type(4))) unsigned int u32x4;

// d_out layout (float32 values):
//   [0, NS)                      assignments (as float)
//   [NS, 2*NS)                   min_dists
//   [2*NS, 2*NS+KK)              leaf_counts
//   [2*NS+KK, +KK*DD)            leaf_sums
//   [2*NS+KK+KK*DD, +KK)         leaf_sum_sq_dist

__global__ void zero_buf(float* __restrict__ p, int n) {
    int i = blockIdx.x * 256 + threadIdx.x;
    if (i < n) p[i] = 0.f;
}

// ws holds ncopy copies of [256 leaves][66 cols] (cols 0..63 sums, 64 cnt, 65 ssq).
// Non-atomic reduce + remap into the output stats layout.
__global__ void reduce_ws(const float* __restrict__ ws, float* __restrict__ o_stats,
                          int ncopy) {
    int e = blockIdx.x * 256 + threadIdx.x;
    if (e >= NSTAT) return;
    float s = 0.f;
    #pragma unroll 4
    for (int j = 0; j < ncopy; ++j) s += ws[(size_t)j * NSTAT + e];
    int leaf = e / 66, c = e - leaf * 66;
    float* o_cnt = o_stats;
    float* o_sum = o_stats + KK;
    float* o_ssq = o_stats + KK + KK * DD;
    if (c < 64)       o_sum[leaf * 64 + c] = s;
    else if (c == 64) o_cnt[leaf] = s;
    else              o_ssq[leaf] = s;
}

__device__ inline unsigned short f2bf(float f) {
    unsigned u = __float_as_uint(f);
    u += 0x7FFFu + ((u >> 16) & 1u);          // round-to-nearest-even
    return (unsigned short)(u >> 16);
}
__device__ inline float bf2f(unsigned short b) {
    return __uint_as_float(((unsigned)b) << 16);
}

// ---------------- K1: MFMA argmin (unchanged from round 5/6, verified) ----------------
__global__ __launch_bounds__(512, 2)
void deepect_argmin(const float* __restrict__ mb, const float* __restrict__ ctr,
                    float* __restrict__ out) {
    __shared__ __align__(16) unsigned short s_ctr[KK][CPAD];  // 36 KB
    __shared__ float s_csq[KK];

    const int tid  = threadIdx.x;
    const int lane = tid & 63;
    const int w    = tid >> 6;
    const int g    = lane >> 4;
    const int c16  = lane & 15;

    for (int idx = tid; idx < KK * 16; idx += 512) {
        int row = idx >> 4, f4 = idx & 15;
        float4 v = ((const float4*)(ctr + row * DD))[f4];
        ushort4 b;
        b.x = f2bf(v.x); b.y = f2bf(v.y); b.z = f2bf(v.z); b.w = f2bf(v.w);
        *(ushort4*)&s_ctr[row][f4 * 4] = b;
    }
    __syncthreads();

    if (tid < KK) {
        float acc = 0.f;
        #pragma unroll
        for (int j = 0; j < 16; ++j) {
            ushort4 b = *(ushort4*)&s_ctr[tid][j * 4];
            float x0 = bf2f(b.x), x1 = bf2f(b.y), x2 = bf2f(b.z), x3 = bf2f(b.w);
            acc += x0 * x0 + x1 * x1 + x2 * x2 + x3 * x3;
        }
        s_csq[tid] = acc;
    }
    __syncthreads();

    float csqh[16];
    #pragma unroll
    for (int t = 0; t < 16; ++t) csqh[t] = -0.5f * s_csq[t * 16 + c16];

    const int sbase = blockIdx.x * 256 + w * 32;

    bf16x8 afr[2][2];
    float  xsq_rt[2];
    #pragma unroll
    for (int rt = 0; rt < 2; ++rt) {
        float px = 0.f;
        #pragma unroll
        for (int ks = 0; ks < 2; ++ks) {
            const float* rp = mb + (size_t)(sbase + rt * 16 + c16) * DD + g * 8 + ks * 32;
            float4 a = ((const float4*)rp)[0];
            float4 b = ((const float4*)rp)[1];
            bf16x8 f;
            f[0] = (short)f2bf(a.x); f[1] = (short)f2bf(a.y);
            f[2] = (short)f2bf(a.z); f[3] = (short)f2bf(a.w);
            f[4] = (short)f2bf(b.x); f[5] = (short)f2bf(b.y);
            f[6] = (short)f2bf(b.z); f[7] = (short)f2bf(b.w);
            afr[rt][ks] = f;
            float q0 = bf2f(f2bf(a.x)), q1 = bf2f(f2bf(a.y)), q2 = bf2f(f2bf(a.z)), q3 = bf2f(f2bf(a.w));
            float q4 = bf2f(f2bf(b.x)), q5 = bf2f(f2bf(b.y)), q6 = bf2f(f2bf(b.z)), q7 = bf2f(f2bf(b.w));
            px += q0*q0 + q1*q1 + q2*q2 + q3*q3 + q4*q4 + q5*q5 + q6*q6 + q7*q7;
        }
        px += __shfl_xor(px, 16, 64);
        px += __shfl_xor(px, 32, 64);
        xsq_rt[rt] = px;
    }

    float bestv[2][4];
    int   besti[2][4];
    #pragma unroll
    for (int rt = 0; rt < 2; ++rt)
        #pragma unroll
        for (int r = 0; r < 4; ++r) { bestv[rt][r] = -FLT_MAX; besti[rt][r] = 0; }

    #pragma unroll
    for (int t = 0; t < 16; ++t) {
        bf16x8 b0 = *(bf16x8*)&s_ctr[t * 16 + c16][g * 8];
        bf16x8 b1 = *(bf16x8*)&s_ctr[t * 16 + c16][g * 8 + 32];
        const int colidx = t * 16 + c16;
        #pragma unroll
        for (int rt = 0; rt < 2; ++rt) {
            f32x4 acc;
            acc[0] = csqh[t]; acc[1] = csqh[t]; acc[2] = csqh[t]; acc[3] = csqh[t];
            acc = __builtin_amdgcn_mfma_f32_16x16x32_bf16(afr[rt][0], b0, acc, 0, 0, 0);
            acc = __builtin_amdgcn_mfma_f32_16x16x32_bf16(afr[rt][1], b1, acc, 0, 0, 0);
            #pragma unroll
            for (int r = 0; r < 4; ++r) {
                if (acc[r] > bestv[rt][r]) { bestv[rt][r] = acc[r]; besti[rt][r] = colidx; }
            }
        }
    }

    float* o_assign = out;
    float* o_mind   = out + NS;

    #pragma unroll
    for (int rt = 0; rt < 2; ++rt) {
        #pragma unroll
        for (int r = 0; r < 4; ++r) {
            float v  = bestv[rt][r];
            int   bi = besti[rt][r];
            #pragma unroll
            for (int off = 1; off < 16; off <<= 1) {
                float ov = __shfl_xor(v, off, 64);
                int   oi = __shfl_xor(bi, off, 64);
                if (ov > v || (ov == v && oi < bi)) { v = ov; bi = oi; }
            }
            int src = (lane & 48) | (g * 4 + r);
            float xq = __shfl(xsq_rt[rt], src, 64);
            float dsq = fmaxf(xq - 2.0f * v, 0.f);
            if (c16 == 0) {
                int s = sbase + rt * 16 + g * 4 + r;
                o_assign[s] = (float)bi;
                o_mind[s]   = sqrtf(dsq);
            }
        }
    }
}

// ---------------- K2: stats as one-hot GEMM (no atomics at all) ----------------
// 512 blocks x 512 threads; block owns 256 samples; C[leaf][col] = sum onehot * B,
// B = [x dims 0..63 | ones col 64 | md^2 col 65 | zeros 66..79].
__global__ __launch_bounds__(512, 2)
void deepect_stats_gemm(const float* __restrict__ mb, const float* __restrict__ out,
                        float* __restrict__ ws) {
    __shared__ __align__(16) unsigned short s_xt[80][XTS];   // 42.2 KB
    __shared__ int s_bi[256];

    const int tid  = threadIdx.x;
    const int lane = tid & 63;
    const int w    = tid >> 6;       // wave 0..7
    const int g    = lane >> 4;
    const int c16  = lane & 15;
    const int base = blockIdx.x * 256;

    unsigned* xtw = (unsigned*)s_xt;

    // zero rows 66..79 (cols 66..79 of B)
    for (int i = tid; i < 14 * XTSW; i += 512) xtw[66 * XTSW + i] = 0u;

    // stage x transposed, two samples packed per dword: thread -> dh (16 dims), sp (2 samples)
    {
        const int dh = tid >> 7, sp = tid & 127;
        const float* r0 = mb + (size_t)(base + 2 * sp) * DD + dh * 16;
        const float* r1 = r0 + DD;
        #pragma unroll
        for (int q = 0; q < 4; ++q) {
            float4 a = ((const float4*)r0)[q];
            float4 b = ((const float4*)r1)[q];
            const int row = dh * 16 + q * 4;
            xtw[(row + 0) * XTSW + sp] = (unsigned)f2bf(a.x) | ((unsigned)f2bf(b.x) << 16);
            xtw[(row + 1) * XTSW + sp] = (unsigned)f2bf(a.y) | ((unsigned)f2bf(b.y) << 16);
            xtw[(row + 2) * XTSW + sp] = (unsigned)f2bf(a.z) | ((unsigned)f2bf(b.z) << 16);
            xtw[(row + 3) * XTSW + sp] = (unsigned)f2bf(a.w) | ((unsigned)f2bf(b.w) << 16);
        }
    }
    if (tid < 128) {
        const int sp = tid;
        float m0 = out[NS + base + 2 * sp];
        float m1 = out[NS + base + 2 * sp + 1];
        xtw[64 * XTSW + sp] = 0x3F803F80u;                                     // ones
        xtw[65 * XTSW + sp] = (unsigned)f2bf(m0 * m0) | ((unsigned)f2bf(m1 * m1) << 16); // md^2
    }
    if (tid < 256) s_bi[tid] = (int)out[base + tid];
    __syncthreads();

    // accumulators: 2 leaf-tiles (w, w+8) x 5 dim-tiles
    f32x4 acc[2][5];
    #pragma unroll
    for (int L = 0; L < 2; ++L)
        #pragma unroll
        for (int dt = 0; dt < 5; ++dt) {
            acc[L][dt][0] = 0.f; acc[L][dt][1] = 0.f;
            acc[L][dt][2] = 0.f; acc[L][dt][3] = 0.f;
        }

    const int ml0 = w * 16 + c16;          // leaf row for tile lt0 = w
    const int ml1 = (w + 8) * 16 + c16;    // leaf row for tile lt1 = w+8

    #pragma unroll
    for (int ks = 0; ks < 8; ++ks) {
        const int kb = ks * 32 + g * 8;
        int4 bl = *(int4*)&s_bi[kb];
        int4 bh = *(int4*)&s_bi[kb + 4];
        bf16x8 bfrag[5];
        #pragma unroll
        for (int dt = 0; dt < 5; ++dt)
            bfrag[dt] = *(bf16x8*)&s_xt[dt * 16 + c16][kb];

        const int b0 = bl.x, b1 = bl.y, b2 = bl.z, b3 = bl.w;
        const int b4 = bh.x, b5 = bh.y, b6 = bh.z, b7 = bh.w;
        u32x4 u0, u1;
        u0[0] = (b0 == ml0 ? 0x3F80u : 0u) | (b1 == ml0 ? 0x3F800000u : 0u);
        u0[1] = (b2 == ml0 ? 0x3F80u : 0u) | (b3 == ml0 ? 0x3F800000u : 0u);
        u0[2] = (b4 == ml0 ? 0x3F80u : 0u) | (b5 == ml0 ? 0x3F800000u : 0u);
        u0[3] = (b6 == ml0 ? 0x3F80u : 0u) | (b7 == ml0 ? 0x3F800000u : 0u);
        u1[0] = (b0 == ml1 ? 0x3F80u : 0u) | (b1 == ml1 ? 0x3F800000u : 0u);
        u1[1] = (b2 == ml1 ? 0x3F80u : 0u) | (b3 == ml1 ? 0x3F800000u : 0u);
        u1[2] = (b4 == ml1 ? 0x3F80u : 0u) | (b5 == ml1 ? 0x3F800000u : 0u);
        u1[3] = (b6 == ml1 ? 0x3F80u : 0u) | (b7 == ml1 ? 0x3F800000u : 0u);
        bf16x8 a0 = __builtin_bit_cast(bf16x8, u0);
        bf16x8 a1 = __builtin_bit_cast(bf16x8, u1);

        #pragma unroll
        for (int dt = 0; dt < 5; ++dt) {
            acc[0][dt] = __builtin_amdgcn_mfma_f32_16x16x32_bf16(a0, bfrag[dt], acc[0][dt], 0, 0, 0);
            acc[1][dt] = __builtin_amdgcn_mfma_f32_16x16x32_bf16(a1, bfrag[dt], acc[1][dt], 0, 0, 0);
        }
    }

    // flush block partials: private copy, layout [leaf][66]
    float* dst = ws + (size_t)blockIdx.x * NSTAT;
    #pragma unroll
    for (int L = 0; L < 2; ++L) {
        const int lt = (L == 0) ? w : (w + 8);
        #pragma unroll
        for (int dt = 0; dt < 5; ++dt) {
            const int col = dt * 16 + c16;
            #pragma unroll
            for (int r = 0; r < 4; ++r) {
                const int leaf = lt * 16 + g * 4 + r;
                if (col < 66) dst[leaf * 66 + col] = acc[L][dt][r];
            }
        }
    }
}

// ---------------- fallback: LDS-atomic stats (only if ws is too small) ----------------
// mode 0: atomic into copy (blockIdx & (ncopy-1)) with [leaf][66] layout (then reduce_ws)
// mode 1: atomic direct into o_stats standard layout (wsdst = o_stats)
__global__ __launch_bounds__(512)
void deepect_stats_atomic(const float* __restrict__ mb, const float* __restrict__ out,
                          float* __restrict__ wsdst, int ncopy, int mode) {
    __shared__ float s_cnt[KK];
    __shared__ float s_ssq[KK];
    __shared__ float s_sum[KK][65];

    const int tid = threadIdx.x;
    for (int idx = tid; idx < KK; idx += 512) { s_cnt[idx] = 0.f; s_ssq[idx] = 0.f; }
    for (int idx = tid; idx < KK * 65; idx += 512) ((float*)s_sum)[idx] = 0.f;
    __syncthreads();

    const int grp = tid >> 4;
    const int d4  = tid & 15;
    const int ibase = blockIdx.x * 512 + grp * 16;

    for (int s = 0; s < 16; ++s) {
        const int i = ibase + s;
        const int bi = (int)out[i];
        float4 v = ((const float4*)(mb + (size_t)i * DD))[d4];
        atomicAdd(&s_sum[bi][d4 * 4 + 0], v.x);
        atomicAdd(&s_sum[bi][d4 * 4 + 1], v.y);
        atomicAdd(&s_sum[bi][d4 * 4 + 2], v.z);
        atomicAdd(&s_sum[bi][d4 * 4 + 3], v.w);
        if (d4 == 0) {
            const float md = out[NS + i];
            atomicAdd(&s_cnt[bi], 1.0f);
            atomicAdd(&s_ssq[bi], md * md);
        }
    }
    __syncthreads();

    if (mode == 0) {
        const size_t cb = (size_t)(blockIdx.x & (ncopy - 1)) * NSTAT;
        for (int idx = tid; idx < KK; idx += 512) {
            atomicAdd(&wsdst[cb + idx * 66 + 64], s_cnt[idx]);
            atomicAdd(&wsdst[cb + idx * 66 + 65], s_ssq[idx]);
        }
        for (int idx = tid; idx < KK * DD; idx += 512)
            atomicAdd(&wsdst[cb + (idx >> 6) * 66 + (idx & 63)], s_sum[idx >> 6][idx & 63]);
    } else {
        for (int idx = tid; idx < KK; idx += 512) {
            atomicAdd(&wsdst[idx], s_cnt[idx]);
            atomicAdd(&wsdst[KK + KK * DD + idx], s_ssq[idx]);
        }
        for (int idx = tid; idx < KK * DD; idx += 512)
            atomicAdd(&wsdst[KK + idx], s_sum[idx >> 6][idx & 63]);
    }
}

extern "C" void kernel_launch(void* const* d_in, const int* in_sizes, int n_in,
                              void* d_out, int out_size, void* d_ws, size_t ws_size,
                              hipStream_t stream) {
    const float* mb  = (const float*)d_in[0];
    const float* ctr = (const float*)d_in[1];
    float* out = (float*)d_out;
    float* o_stats = out + 2 * NS;
    float* ws = (float*)d_ws;

    hipLaunchKernelGGL(deepect_argmin, dim3(NS / 256), dim3(512), 0, stream,
                       mb, ctr, out);

    const size_t need512 = (size_t)512 * NSTAT * sizeof(float);  // 34.6 MB
    const size_t need64  = (size_t)64  * NSTAT * sizeof(float);  //  4.3 MB

    if (ws_size >= need512) {
        // fast path: one-hot GEMM stats, no atomics anywhere
        hipLaunchKernelGGL(deepect_stats_gemm, dim3(NS / 256), dim3(512), 0, stream,
                           mb, out, ws);
        hipLaunchKernelGGL(reduce_ws, dim3((NSTAT + 255) / 256), dim3(256), 0, stream,
                           ws, o_stats, 512);
    } else if (ws_size >= need64) {
        hipLaunchKernelGGL(zero_buf, dim3((64 * NSTAT + 255) / 256), dim3(256), 0,
                           stream, ws, 64 * NSTAT);
        hipLaunchKernelGGL(deepect_stats_atomic, dim3(NS / 512), dim3(512), 0, stream,
                           mb, out, ws, 64, 0);
        hipLaunchKernelGGL(reduce_ws, dim3((NSTAT + 255) / 256), dim3(256), 0, stream,
                           ws, o_stats, 64);
    } else {
        hipLaunchKernelGGL(zero_buf, dim3((NSTAT + 255) / 256), dim3(256), 0, stream,
                           o_stats, NSTAT);
        hipLaunchKernelGGL(deepect_stats_atomic, dim3(NS / 512), dim3(512), 0, stream,
                           mb, out, o_stats, 1, 1);
    }
}

// Round 8
// 50.218 us; speedup vs baseline: 2.0965x; 1.6979x over previous
//
#include <hip/hip_runtime.h>
#include <float.h>

#define NS 131072
#define DD 64
#define KK 256
#define CPAD 72     // argmin center tile pad (unchanged, verified)
#define NSTAT 16896 // 256 * 66  (== KK + KK*DD + KK values)
#define XTS 264     // xT row stride in bf16
#define XTSW 132    // XTS/2 dwords
#define NCOPY 512
#define RGROUPS 16
#define RPER 32     // NCOPY / RGROUPS

typedef __attribute__((ext_vector_type(8))) short bf16x8;
typedef __attribute__((ext_vector_type(4))) float f32x4;
typedef __attribute__((ext_vector_type(4))) unsigned int u32x4;

// d_out layout (float32 values):
//   [0, NS)                      assignments (as float)
//   [NS, 2*NS)                   min_dists
//   [2*NS, 2*NS+KK)              leaf_counts
//   [2*NS+KK, +KK*DD)            leaf_sums
//   [2*NS+KK+KK*DD, +KK)         leaf_sum_sq_dist

__global__ void zero_buf(float* __restrict__ p, int n) {
    int i = blockIdx.x * 256 + threadIdx.x;
    if (i < n) p[i] = 0.f;
}

// ---- two-stage reduce over NCOPY copies of [256][66] partials ----
// Stage 1: thread (g,e) sums copies [g*RPER,(g+1)*RPER) at element e, writes the
// partial in place into copy (g*RPER). Sole toucher of those addresses -> safe.
__global__ void reduce_ws1(float* __restrict__ ws) {
    int gid = blockIdx.x * 256 + threadIdx.x;
    if (gid >= NSTAT * RGROUPS) return;
    int g = gid / NSTAT, e = gid - g * NSTAT;
    const float* src = ws + (size_t)(g * RPER) * NSTAT + e;
    float s = 0.f;
    #pragma unroll 8
    for (int j = 0; j < RPER; ++j) s += src[(size_t)j * NSTAT];
    ws[(size_t)(g * RPER) * NSTAT + e] = s;
}

// Stage 2: sum the RGROUPS partials (stride RPER*NSTAT), remap to output layout.
__global__ void reduce_ws2(const float* __restrict__ ws, float* __restrict__ o_stats) {
    int e = blockIdx.x * 256 + threadIdx.x;
    if (e >= NSTAT) return;
    float s = 0.f;
    #pragma unroll
    for (int g = 0; g < RGROUPS; ++g) s += ws[(size_t)(g * RPER) * NSTAT + e];
    int leaf = e / 66, c = e - leaf * 66;
    float* o_cnt = o_stats;
    float* o_sum = o_stats + KK;
    float* o_ssq = o_stats + KK + KK * DD;
    if (c < 64)       o_sum[leaf * 64 + c] = s;
    else if (c == 64) o_cnt[leaf] = s;
    else              o_ssq[leaf] = s;
}

// single-stage reduce (fallback paths only)
__global__ void reduce_ws(const float* __restrict__ ws, float* __restrict__ o_stats,
                          int ncopy) {
    int e = blockIdx.x * 256 + threadIdx.x;
    if (e >= NSTAT) return;
    float s = 0.f;
    #pragma unroll 8
    for (int j = 0; j < ncopy; ++j) s += ws[(size_t)j * NSTAT + e];
    int leaf = e / 66, c = e - leaf * 66;
    float* o_cnt = o_stats;
    float* o_sum = o_stats + KK;
    float* o_ssq = o_stats + KK + KK * DD;
    if (c < 64)       o_sum[leaf * 64 + c] = s;
    else if (c == 64) o_cnt[leaf] = s;
    else              o_ssq[leaf] = s;
}

__device__ inline unsigned short f2bf(float f) {
    unsigned u = __float_as_uint(f);
    u += 0x7FFFu + ((u >> 16) & 1u);          // round-to-nearest-even
    return (unsigned short)(u >> 16);
}
__device__ inline float bf2f(unsigned short b) {
    return __uint_as_float(((unsigned)b) << 16);
}

// ---------------- K1: MFMA argmin (unchanged, verified) ----------------
__global__ __launch_bounds__(512, 2)
void deepect_argmin(const float* __restrict__ mb, const float* __restrict__ ctr,
                    float* __restrict__ out) {
    __shared__ __align__(16) unsigned short s_ctr[KK][CPAD];  // 36 KB
    __shared__ float s_csq[KK];

    const int tid  = threadIdx.x;
    const int lane = tid & 63;
    const int w    = tid >> 6;
    const int g    = lane >> 4;
    const int c16  = lane & 15;

    for (int idx = tid; idx < KK * 16; idx += 512) {
        int row = idx >> 4, f4 = idx & 15;
        float4 v = ((const float4*)(ctr + row * DD))[f4];
        ushort4 b;
        b.x = f2bf(v.x); b.y = f2bf(v.y); b.z = f2bf(v.z); b.w = f2bf(v.w);
        *(ushort4*)&s_ctr[row][f4 * 4] = b;
    }
    __syncthreads();

    if (tid < KK) {
        float acc = 0.f;
        #pragma unroll
        for (int j = 0; j < 16; ++j) {
            ushort4 b = *(ushort4*)&s_ctr[tid][j * 4];
            float x0 = bf2f(b.x), x1 = bf2f(b.y), x2 = bf2f(b.z), x3 = bf2f(b.w);
            acc += x0 * x0 + x1 * x1 + x2 * x2 + x3 * x3;
        }
        s_csq[tid] = acc;
    }
    __syncthreads();

    float csqh[16];
    #pragma unroll
    for (int t = 0; t < 16; ++t) csqh[t] = -0.5f * s_csq[t * 16 + c16];

    const int sbase = blockIdx.x * 256 + w * 32;

    bf16x8 afr[2][2];
    float  xsq_rt[2];
    #pragma unroll
    for (int rt = 0; rt < 2; ++rt) {
        float px = 0.f;
        #pragma unroll
        for (int ks = 0; ks < 2; ++ks) {
            const float* rp = mb + (size_t)(sbase + rt * 16 + c16) * DD + g * 8 + ks * 32;
            float4 a = ((const float4*)rp)[0];
            float4 b = ((const float4*)rp)[1];
            bf16x8 f;
            f[0] = (short)f2bf(a.x); f[1] = (short)f2bf(a.y);
            f[2] = (short)f2bf(a.z); f[3] = (short)f2bf(a.w);
            f[4] = (short)f2bf(b.x); f[5] = (short)f2bf(b.y);
            f[6] = (short)f2bf(b.z); f[7] = (short)f2bf(b.w);
            afr[rt][ks] = f;
            float q0 = bf2f(f2bf(a.x)), q1 = bf2f(f2bf(a.y)), q2 = bf2f(f2bf(a.z)), q3 = bf2f(f2bf(a.w));
            float q4 = bf2f(f2bf(b.x)), q5 = bf2f(f2bf(b.y)), q6 = bf2f(f2bf(b.z)), q7 = bf2f(f2bf(b.w));
            px += q0*q0 + q1*q1 + q2*q2 + q3*q3 + q4*q4 + q5*q5 + q6*q6 + q7*q7;
        }
        px += __shfl_xor(px, 16, 64);
        px += __shfl_xor(px, 32, 64);
        xsq_rt[rt] = px;
    }

    float bestv[2][4];
    int   besti[2][4];
    #pragma unroll
    for (int rt = 0; rt < 2; ++rt)
        #pragma unroll
        for (int r = 0; r < 4; ++r) { bestv[rt][r] = -FLT_MAX; besti[rt][r] = 0; }

    #pragma unroll
    for (int t = 0; t < 16; ++t) {
        bf16x8 b0 = *(bf16x8*)&s_ctr[t * 16 + c16][g * 8];
        bf16x8 b1 = *(bf16x8*)&s_ctr[t * 16 + c16][g * 8 + 32];
        const int colidx = t * 16 + c16;
        #pragma unroll
        for (int rt = 0; rt < 2; ++rt) {
            f32x4 acc;
            acc[0] = csqh[t]; acc[1] = csqh[t]; acc[2] = csqh[t]; acc[3] = csqh[t];
            acc = __builtin_amdgcn_mfma_f32_16x16x32_bf16(afr[rt][0], b0, acc, 0, 0, 0);
            acc = __builtin_amdgcn_mfma_f32_16x16x32_bf16(afr[rt][1], b1, acc, 0, 0, 0);
            #pragma unroll
            for (int r = 0; r < 4; ++r) {
                if (acc[r] > bestv[rt][r]) { bestv[rt][r] = acc[r]; besti[rt][r] = colidx; }
            }
        }
    }

    float* o_assign = out;
    float* o_mind   = out + NS;

    #pragma unroll
    for (int rt = 0; rt < 2; ++rt) {
        #pragma unroll
        for (int r = 0; r < 4; ++r) {
            float v  = bestv[rt][r];
            int   bi = besti[rt][r];
            #pragma unroll
            for (int off = 1; off < 16; off <<= 1) {
                float ov = __shfl_xor(v, off, 64);
                int   oi = __shfl_xor(bi, off, 64);
                if (ov > v || (ov == v && oi < bi)) { v = ov; bi = oi; }
            }
            int src = (lane & 48) | (g * 4 + r);
            float xq = __shfl(xsq_rt[rt], src, 64);
            float dsq = fmaxf(xq - 2.0f * v, 0.f);
            if (c16 == 0) {
                int s = sbase + rt * 16 + g * 4 + r;
                o_assign[s] = (float)bi;
                o_mind[s]   = sqrtf(dsq);
            }
        }
    }
}

// ---------------- K2: stats as one-hot GEMM (no atomics, verified) ----------------
__global__ __launch_bounds__(512, 2)
void deepect_stats_gemm(const float* __restrict__ mb, const float* __restrict__ out,
                        float* __restrict__ ws) {
    __shared__ __align__(16) unsigned short s_xt[80][XTS];   // 42.2 KB
    __shared__ int s_bi[256];

    const int tid  = threadIdx.x;
    const int lane = tid & 63;
    const int w    = tid >> 6;
    const int g    = lane >> 4;
    const int c16  = lane & 15;
    const int base = blockIdx.x * 256;

    unsigned* xtw = (unsigned*)s_xt;

    for (int i = tid; i < 14 * XTSW; i += 512) xtw[66 * XTSW + i] = 0u;

    {
        const int dh = tid >> 7, sp = tid & 127;
        const float* r0 = mb + (size_t)(base + 2 * sp) * DD + dh * 16;
        const float* r1 = r0 + DD;
        #pragma unroll
        for (int q = 0; q < 4; ++q) {
            float4 a = ((const float4*)r0)[q];
            float4 b = ((const float4*)r1)[q];
            const int row = dh * 16 + q * 4;
            xtw[(row + 0) * XTSW + sp] = (unsigned)f2bf(a.x) | ((unsigned)f2bf(b.x) << 16);
            xtw[(row + 1) * XTSW + sp] = (unsigned)f2bf(a.y) | ((unsigned)f2bf(b.y) << 16);
            xtw[(row + 2) * XTSW + sp] = (unsigned)f2bf(a.z) | ((unsigned)f2bf(b.z) << 16);
            xtw[(row + 3) * XTSW + sp] = (unsigned)f2bf(a.w) | ((unsigned)f2bf(b.w) << 16);
        }
    }
    if (tid < 128) {
        const int sp = tid;
        float m0 = out[NS + base + 2 * sp];
        float m1 = out[NS + base + 2 * sp + 1];
        xtw[64 * XTSW + sp] = 0x3F803F80u;
        xtw[65 * XTSW + sp] = (unsigned)f2bf(m0 * m0) | ((unsigned)f2bf(m1 * m1) << 16);
    }
    if (tid < 256) s_bi[tid] = (int)out[base + tid];
    __syncthreads();

    f32x4 acc[2][5];
    #pragma unroll
    for (int L = 0; L < 2; ++L)
        #pragma unroll
        for (int dt = 0; dt < 5; ++dt) {
            acc[L][dt][0] = 0.f; acc[L][dt][1] = 0.f;
            acc[L][dt][2] = 0.f; acc[L][dt][3] = 0.f;
        }

    const int ml0 = w * 16 + c16;
    const int ml1 = (w + 8) * 16 + c16;

    #pragma unroll
    for (int ks = 0; ks < 8; ++ks) {
        const int kb = ks * 32 + g * 8;
        int4 bl = *(int4*)&s_bi[kb];
        int4 bh = *(int4*)&s_bi[kb + 4];
        bf16x8 bfrag[5];
        #pragma unroll
        for (int dt = 0; dt < 5; ++dt)
            bfrag[dt] = *(bf16x8*)&s_xt[dt * 16 + c16][kb];

        const int b0 = bl.x, b1 = bl.y, b2 = bl.z, b3 = bl.w;
        const int b4 = bh.x, b5 = bh.y, b6 = bh.z, b7 = bh.w;
        u32x4 u0, u1;
        u0[0] = (b0 == ml0 ? 0x3F80u : 0u) | (b1 == ml0 ? 0x3F800000u : 0u);
        u0[1] = (b2 == ml0 ? 0x3F80u : 0u) | (b3 == ml0 ? 0x3F800000u : 0u);
        u0[2] = (b4 == ml0 ? 0x3F80u : 0u) | (b5 == ml0 ? 0x3F800000u : 0u);
        u0[3] = (b6 == ml0 ? 0x3F80u : 0u) | (b7 == ml0 ? 0x3F800000u : 0u);
        u1[0] = (b0 == ml1 ? 0x3F80u : 0u) | (b1 == ml1 ? 0x3F800000u : 0u);
        u1[1] = (b2 == ml1 ? 0x3F80u : 0u) | (b3 == ml1 ? 0x3F800000u : 0u);
        u1[2] = (b4 == ml1 ? 0x3F80u : 0u) | (b5 == ml1 ? 0x3F800000u : 0u);
        u1[3] = (b6 == ml1 ? 0x3F80u : 0u) | (b7 == ml1 ? 0x3F800000u : 0u);
        bf16x8 a0 = __builtin_bit_cast(bf16x8, u0);
        bf16x8 a1 = __builtin_bit_cast(bf16x8, u1);

        #pragma unroll
        for (int dt = 0; dt < 5; ++dt) {
            acc[0][dt] = __builtin_amdgcn_mfma_f32_16x16x32_bf16(a0, bfrag[dt], acc[0][dt], 0, 0, 0);
            acc[1][dt] = __builtin_amdgcn_mfma_f32_16x16x32_bf16(a1, bfrag[dt], acc[1][dt], 0, 0, 0);
        }
    }

    float* dst = ws + (size_t)blockIdx.x * NSTAT;
    #pragma unroll
    for (int L = 0; L < 2; ++L) {
        const int lt = (L == 0) ? w : (w + 8);
        #pragma unroll
        for (int dt = 0; dt < 5; ++dt) {
            const int col = dt * 16 + c16;
            #pragma unroll
            for (int r = 0; r < 4; ++r) {
                const int leaf = lt * 16 + g * 4 + r;
                if (col < 66) dst[leaf * 66 + col] = acc[L][dt][r];
            }
        }
    }
}

// ---------------- fallback: LDS-atomic stats (only if ws is too small) ----------------
__global__ __launch_bounds__(512)
void deepect_stats_atomic(const float* __restrict__ mb, const float* __restrict__ out,
                          float* __restrict__ wsdst, int ncopy, int mode) {
    __shared__ float s_cnt[KK];
    __shared__ float s_ssq[KK];
    __shared__ float s_sum[KK][65];

    const int tid = threadIdx.x;
    for (int idx = tid; idx < KK; idx += 512) { s_cnt[idx] = 0.f; s_ssq[idx] = 0.f; }
    for (int idx = tid; idx < KK * 65; idx += 512) ((float*)s_sum)[idx] = 0.f;
    __syncthreads();

    const int grp = tid >> 4;
    const int d4  = tid & 15;
    const int ibase = blockIdx.x * 512 + grp * 16;

    for (int s = 0; s < 16; ++s) {
        const int i = ibase + s;
        const int bi = (int)out[i];
        float4 v = ((const float4*)(mb + (size_t)i * DD))[d4];
        atomicAdd(&s_sum[bi][d4 * 4 + 0], v.x);
        atomicAdd(&s_sum[bi][d4 * 4 + 1], v.y);
        atomicAdd(&s_sum[bi][d4 * 4 + 2], v.z);
        atomicAdd(&s_sum[bi][d4 * 4 + 3], v.w);
        if (d4 == 0) {
            const float md = out[NS + i];
            atomicAdd(&s_cnt[bi], 1.0f);
            atomicAdd(&s_ssq[bi], md * md);
        }
    }
    __syncthreads();

    if (mode == 0) {
        const size_t cb = (size_t)(blockIdx.x & (ncopy - 1)) * NSTAT;
        for (int idx = tid; idx < KK; idx += 512) {
            atomicAdd(&wsdst[cb + idx * 66 + 64], s_cnt[idx]);
            atomicAdd(&wsdst[cb + idx * 66 + 65], s_ssq[idx]);
        }
        for (int idx = tid; idx < KK * DD; idx += 512)
            atomicAdd(&wsdst[cb + (idx >> 6) * 66 + (idx & 63)], s_sum[idx >> 6][idx & 63]);
    } else {
        for (int idx = tid; idx < KK; idx += 512) {
            atomicAdd(&wsdst[idx], s_cnt[idx]);
            atomicAdd(&wsdst[KK + KK * DD + idx], s_ssq[idx]);
        }
        for (int idx = tid; idx < KK * DD; idx += 512)
            atomicAdd(&wsdst[KK + idx], s_sum[idx >> 6][idx & 63]);
    }
}

extern "C" void kernel_launch(void* const* d_in, const int* in_sizes, int n_in,
                              void* d_out, int out_size, void* d_ws, size_t ws_size,
                              hipStream_t stream) {
    const float* mb  = (const float*)d_in[0];
    const float* ctr = (const float*)d_in[1];
    float* out = (float*)d_out;
    float* o_stats = out + 2 * NS;
    float* ws = (float*)d_ws;

    hipLaunchKernelGGL(deepect_argmin, dim3(NS / 256), dim3(512), 0, stream,
                       mb, ctr, out);

    const size_t need512 = (size_t)NCOPY * NSTAT * sizeof(float);  // 34.6 MB
    const size_t need64  = (size_t)64    * NSTAT * sizeof(float);  //  4.3 MB

    if (ws_size >= need512) {
        // fast path: one-hot GEMM stats + two-stage parallel reduce, no atomics
        hipLaunchKernelGGL(deepect_stats_gemm, dim3(NS / 256), dim3(512), 0, stream,
                           mb, out, ws);
        hipLaunchKernelGGL(reduce_ws1, dim3((NSTAT * RGROUPS + 255) / 256), dim3(256),
                           0, stream, ws);
        hipLaunchKernelGGL(reduce_ws2, dim3((NSTAT + 255) / 256), dim3(256), 0, stream,
                           ws, o_stats);
    } else if (ws_size >= need64) {
        hipLaunchKernelGGL(zero_buf, dim3((64 * NSTAT + 255) / 256), dim3(256), 0,
                           stream, ws, 64 * NSTAT);
        hipLaunchKernelGGL(deepect_stats_atomic, dim3(NS / 512), dim3(512), 0, stream,
                           mb, out, ws, 64, 0);
        hipLaunchKernelGGL(reduce_ws, dim3((NSTAT + 255) / 256), dim3(256), 0, stream,
                           ws, o_stats, 64);
    } else {
        hipLaunchKernelGGL(zero_buf, dim3((NSTAT + 255) / 256), dim3(256), 0, stream,
                           o_stats, NSTAT);
        hipLaunchKernelGGL(deepect_stats_atomic, dim3(NS / 512), dim3(512), 0, stream,
                           mb, out, o_stats, 1, 1);
    }
}